// Round 22
// baseline (456.106 us; speedup 1.0000x reference)
//
#include <hip/hip_runtime.h>

#define H 128

typedef __attribute__((ext_vector_type(8))) short bf16x8;
typedef __attribute__((ext_vector_type(4))) float f32x4;

__device__ __forceinline__ float bf2f(unsigned short u) {
    return __uint_as_float(((unsigned)u) << 16);
}
__device__ __forceinline__ unsigned short f2bf(float f) {
    unsigned u = __float_as_uint(f);
    unsigned r = (u + 0x7fffu + ((u >> 16) & 1u)) >> 16;
    return (unsigned short)r;
}
__device__ __forceinline__ unsigned pack2bf(float a, float b) {
    return (unsigned)f2bf(a) | ((unsigned)f2bf(b) << 16);
}

// ---------------- fuse: MFMA K=32, bf16 out (+ zeroes accum/bukTot in block 0) ----------------
__global__ void fuse_kernel(const float* __restrict__ x,
                            const float* __restrict__ sat_w, const float* __restrict__ sat_b,
                            const float* __restrict__ neigh_w, const float* __restrict__ neigh_b,
                            const float* __restrict__ fus_w, const float* __restrict__ fus_b,
                            unsigned short* __restrict__ h0b,
                            float* __restrict__ accum, int* __restrict__ bukTot, int N) {
    __shared__ unsigned smem[8512];
    __shared__ float reds[4][64];
    unsigned* a_lds = smem;
    unsigned* w_lds = smem + 2304;
    int tid = threadIdx.x;
    int base = blockIdx.x * 64;
    if (blockIdx.x == 0) {
        for (int i = tid; i < 4096; i += 256) accum[i] = 0.f;
        bukTot[tid] = 0;
    }
    for (int i = tid; i < 64 * 32; i += 256) {
        int n = i >> 5, kp = i & 31;
        int gn = base + n;
        float2 v = (gn < N) ? *(const float2*)(x + (size_t)gn * 64 + kp * 2) : make_float2(0.f, 0.f);
        a_lds[n * 36 + kp] = pack2bf(v.x, v.y);
    }
    for (int i = tid; i < 256 * 16; i += 256) {
        int r = i >> 4, kp = i & 15;
        const float* wsrc = (r < 128) ? (sat_w + (size_t)r * 32) : (neigh_w + (size_t)(r - 128) * 32);
        float2 v = *(const float2*)(wsrc + kp * 2);
        w_lds[r * 20 + kp] = pack2bf(v.x, v.y);
    }
    __syncthreads();
    int lane = tid & 63;
    int wv = tid >> 6;
    int lr = lane & 15, lk = lane >> 4;
    f32x4 accS[4][2], accN[4][2];
#pragma unroll
    for (int r = 0; r < 4; ++r)
#pragma unroll
        for (int t = 0; t < 2; ++t) {
            accS[r][t] = (f32x4){0.f, 0.f, 0.f, 0.f};
            accN[r][t] = (f32x4){0.f, 0.f, 0.f, 0.f};
        }
    bf16x8 afS[4], afN[4];
#pragma unroll
    for (int r = 0; r < 4; ++r) {
        afS[r] = *(const bf16x8*)&a_lds[(r * 16 + lr) * 36 + lk * 4];
        afN[r] = *(const bf16x8*)&a_lds[(r * 16 + lr) * 36 + 16 + lk * 4];
    }
#pragma unroll
    for (int t = 0; t < 2; ++t) {
        bf16x8 bS = *(const bf16x8*)&w_lds[(wv * 32 + t * 16 + lr) * 20 + lk * 4];
        bf16x8 bN = *(const bf16x8*)&w_lds[(128 + wv * 32 + t * 16 + lr) * 20 + lk * 4];
#pragma unroll
        for (int r = 0; r < 4; ++r) {
            accS[r][t] = __builtin_amdgcn_mfma_f32_16x16x32_bf16(afS[r], bS, accS[r][t], 0, 0, 0);
            accN[r][t] = __builtin_amdgcn_mfma_f32_16x16x32_bf16(afN[r], bN, accN[r][t], 0, 0, 0);
        }
    }
    __syncthreads();
    unsigned short* cst = (unsigned short*)smem; // [64][266]
#pragma unroll
    for (int t = 0; t < 2; ++t) {
        int col = wv * 32 + t * 16 + lr;
        float sb = sat_b[col], nb = neigh_b[col];
#pragma unroll
        for (int r = 0; r < 4; ++r) {
#pragma unroll
            for (int j = 0; j < 4; ++j) {
                int srow = r * 16 + lk * 4 + j;
                cst[srow * 266 + col] = f2bf(fmaxf(accS[r][t][j] + sb, 0.f));
                cst[srow * 266 + 133 + col] = f2bf(fmaxf(accN[r][t][j] + nb, 0.f));
            }
        }
    }
    __syncthreads();
    int node = tid & 63;
    int part = tid >> 6;
    float ps = 0.f;
#pragma unroll
    for (int k = 0; k < 32; ++k) {
        int col = part * 32 + k;
        ps += bf2f(cst[node * 266 + col]) * fus_w[col]
            + bf2f(cst[node * 266 + 133 + col]) * fus_w[128 + col];
    }
    reds[part][node] = ps;
    __syncthreads();
    float tot = reds[0][node] + reds[1][node] + reds[2][node] + reds[3][node];
    float g = 1.f / (1.f + __expf(-(tot + fus_b[0])));
    if (base + node < N) {
        unsigned* op = (unsigned*)h0b + (size_t)(base + node) * 64 + part * 16;
#pragma unroll
        for (int kp = 0; kp < 16; ++kp) {
            int col = part * 32 + kp * 2;
            float o0 = g * bf2f(cst[node * 266 + col]) + (1.f - g) * bf2f(cst[node * 266 + 133 + col]);
            float o1 = g * bf2f(cst[node * 266 + col + 1]) + (1.f - g) * bf2f(cst[node * 266 + 134 + col]);
            op[kp] = pack2bf(o0, o1);
        }
    }
}

// ---------------- MFMA bf16 GEMM ----------------
template <int TAG, int MODE>
__global__ void gemm128m(const void* __restrict__ inv, const float* __restrict__ w,
                         const float* __restrict__ bias, int do_relu,
                         unsigned short* __restrict__ outb, int N,
                         const float* __restrict__ a_sp, const float* __restrict__ a_dp,
                         float* __restrict__ al_s, float* __restrict__ al_d,
                         const float* __restrict__ accum8, const float* __restrict__ gvec,
                         const float* __restrict__ bevec,
                         const unsigned short* __restrict__ resb, unsigned* __restrict__ yout) {
    __shared__ unsigned a_lds[64 * 68];
    __shared__ unsigned w_lds[128 * 68];
    __shared__ float reds[4][64];
    __shared__ float redd[4][64];
    __shared__ float sc_l[128], sh_l[128];
    int tid = threadIdx.x;
    int base = blockIdx.x * 64;
    if (MODE == 2) {
        if (tid < 128) {
            float s = 0.f, q = 0.f;
#pragma unroll
            for (int c = 0; c < 8; ++c) {
                s += accum8[c * 256 + tid];
                q += accum8[c * 256 + 128 + tid];
            }
            float Ninv = 1.f / (float)N;
            float mu = s * Ninv;
            float var = q * Ninv - mu * mu;
            float sc = rsqrtf(var + 1e-5f) * gvec[tid];
            sc_l[tid] = sc;
            sh_l[tid] = bevec[tid] - mu * sc;
        }
        __syncthreads();
    }
    for (int i = tid; i < 64 * 64; i += 256) {
        int n = i >> 6, kp = i & 63;
        int gn = base + n;
        unsigned p = 0u;
        if (gn < N) {
            if (MODE == 1) {
                p = ((const unsigned*)inv)[(size_t)gn * 64 + kp];
            } else {
                float2 v = *(const float2*)((const float*)inv + (size_t)gn * 128 + kp * 2);
                float2 sc = ((const float2*)sc_l)[kp];
                float2 sh = ((const float2*)sh_l)[kp];
                ushort2 rr = ((const ushort2*)(resb + (size_t)gn * 128))[kp];
                float y0 = fmaxf(v.x * sc.x + sh.x, 0.f) + bf2f(rr.x);
                float y1 = fmaxf(v.y * sc.y + sh.y, 0.f) + bf2f(rr.y);
                p = pack2bf(y0, y1);
                if (yout) yout[(size_t)gn * 64 + kp] = p;
            }
        }
        a_lds[n * 68 + kp] = p;
    }
    for (int i = tid; i < 128 * 64; i += 256) {
        int c = i >> 6, kp = i & 63;
        float2 v = *(const float2*)(w + (size_t)c * 128 + kp * 2);
        w_lds[c * 68 + kp] = pack2bf(v.x, v.y);
    }
    __syncthreads();
    int lane = tid & 63;
    int wv = tid >> 6;
    int lr = lane & 15;
    int lk = lane >> 4;
    f32x4 acc[4][2];
#pragma unroll
    for (int r = 0; r < 4; ++r)
#pragma unroll
        for (int t = 0; t < 2; ++t) acc[r][t] = (f32x4){0.f, 0.f, 0.f, 0.f};
    for (int c = 0; c < 4; ++c) {
        bf16x8 af[4], bfr[2];
#pragma unroll
        for (int r = 0; r < 4; ++r)
            af[r] = *(const bf16x8*)&a_lds[(r * 16 + lr) * 68 + c * 16 + lk * 4];
#pragma unroll
        for (int t = 0; t < 2; ++t)
            bfr[t] = *(const bf16x8*)&w_lds[(wv * 32 + t * 16 + lr) * 68 + c * 16 + lk * 4];
#pragma unroll
        for (int r = 0; r < 4; ++r)
#pragma unroll
            for (int t = 0; t < 2; ++t)
                acc[r][t] = __builtin_amdgcn_mfma_f32_16x16x32_bf16(af[r], bfr[t], acc[r][t], 0, 0, 0);
    }
    __syncthreads();
    unsigned short* cst = (unsigned short*)a_lds; // [64][136]
#pragma unroll
    for (int t = 0; t < 2; ++t) {
        int col = wv * 32 + t * 16 + lr;
        float bv = bias ? bias[col] : 0.f;
#pragma unroll
        for (int r = 0; r < 4; ++r) {
#pragma unroll
            for (int j = 0; j < 4; ++j) {
                float v = acc[r][t][j] + bv;
                if (do_relu) v = fmaxf(v, 0.f);
                cst[(r * 16 + lk * 4 + j) * 136 + col] = f2bf(v);
            }
        }
    }
    __syncthreads();
    for (int i = tid; i < 64 * 64; i += 256) {
        int n = i >> 6, kp = i & 63;
        int gn = base + n;
        if (gn < N) ((unsigned*)outb)[(size_t)gn * 64 + kp] = a_lds[n * 68 + kp];
    }
    if (a_sp) {
        int node = tid & 63;
        int part = tid >> 6;
        float ps = 0.f, pd = 0.f;
        int kb = part * 32;
        const unsigned short* xr = cst + node * 136 + kb;
#pragma unroll
        for (int k = 0; k < 32; ++k) {
            float v = bf2f(xr[k]);
            ps += v * a_sp[kb + k];
            pd += v * a_dp[kb + k];
        }
        reds[part][node] = ps;
        redd[part][node] = pd;
        __syncthreads();
        if (tid < 64) {
            int gn = base + tid;
            if (gn < N) {
                al_s[gn] = reds[0][tid] + reds[1][tid] + reds[2][tid] + reds[3][tid];
                al_d[gn] = redd[0][tid] + redd[1][tid] + redd[2][tid] + redd[3][tid];
            }
        }
    }
}

// ---------------- CSR build: streaming bucket sort ----------------
#define PBMAX 6400
#define NBSTR 256
__global__ void pack_bucket(const int* __restrict__ src, const int* __restrict__ dst,
                            unsigned* __restrict__ pk2, int* __restrict__ cntBB,
                            int* __restrict__ offBB, int* __restrict__ bukTot, int E, int PB) {
    __shared__ unsigned opk[PBMAX];
    __shared__ unsigned opk2[PBMAX];
    __shared__ int lcnt[256];
    __shared__ int tmp[256];
    int tid = threadIdx.x;
    int blk = blockIdx.x;
    int e0 = blk * PB;
    int n = min(PB, E - e0);
    if (n < 0) n = 0;
    lcnt[tid] = 0;
    __syncthreads();
    for (int i = tid; i < n; i += 256) {
        int s = src[e0 + i];
        int d = dst[e0 + i];
        unsigned p = ((unsigned)d << 16) | (unsigned)s;
        opk[i] = p;
        atomicAdd(&lcnt[d >> 8], 1);
    }
    __syncthreads();
    int v = lcnt[tid];
    tmp[tid] = v;
    __syncthreads();
    for (int off = 1; off < 256; off <<= 1) {
        int u = (tid >= off) ? tmp[tid - off] : 0;
        __syncthreads();
        tmp[tid] += u;
        __syncthreads();
    }
    int excl = tmp[tid] - v;
    cntBB[(size_t)tid * NBSTR + blk] = v;
    offBB[(size_t)tid * NBSTR + blk] = excl;
    if (v > 0) atomicAdd(&bukTot[tid], v);
    lcnt[tid] = excl;
    __syncthreads();
    for (int i = tid; i < n; i += 256) {
        unsigned p = opk[i];
        int pos = atomicAdd(&lcnt[(p >> 16) >> 8], 1);
        opk2[pos] = p;
    }
    __syncthreads();
    for (int i = tid; i < n; i += 256) pk2[e0 + i] = opk2[i];
}

#define BCAP 10240
__global__ void scatter_sort2(const unsigned* __restrict__ pk2, const int* __restrict__ cntBB,
                              const int* __restrict__ offBB, const int* __restrict__ bukTot,
                              int* __restrict__ ssrc, int* __restrict__ rowptr,
                              int N, int E, int PB) {
    __shared__ int segoff[257];
    __shared__ int segsrc[256];
    __shared__ int segcnt[256];
    __shared__ int lcur[256];
    __shared__ int tmp[256];
    __shared__ int bt[256];
    __shared__ int gb_sh;
    __shared__ unsigned opk[BCAP];
    __shared__ int osrc[BCAP];
    int b = blockIdx.x;
    int d0 = b << 8;
    int tid = threadIdx.x;
    int btv = bukTot[tid];
    bt[tid] = btv;
    tmp[tid] = btv;
    __syncthreads();
    for (int off = 1; off < 256; off <<= 1) {
        int u = (tid >= off) ? tmp[tid - off] : 0;
        __syncthreads();
        tmp[tid] += u;
        __syncthreads();
    }
    if (tid == 0) {
        gb_sh = tmp[b] - bt[b];
        if (b == 0) rowptr[N] = E;
    }
    __syncthreads();
    int c = cntBB[(size_t)b * NBSTR + tid];
    segcnt[tid] = c;
    segsrc[tid] = tid * PB + offBB[(size_t)b * NBSTR + tid];
    tmp[tid] = c;
    lcur[tid] = 0;
    __syncthreads();
    for (int off = 1; off < 256; off <<= 1) {
        int u = (tid >= off) ? tmp[tid - off] : 0;
        __syncthreads();
        tmp[tid] += u;
        __syncthreads();
    }
    segoff[tid] = tmp[tid] - segcnt[tid];
    if (tid == 255) segoff[256] = tmp[255];
    __syncthreads();
    int cntb = segoff[256];
    int wv = tid >> 6, lane = tid & 63;
    for (int s = wv; s < 256; s += 4) {
        int sc = segcnt[s], so = segoff[s], gs = segsrc[s];
        for (int i = lane; i < sc; i += 64) opk[so + i] = pk2[gs + i];
    }
    __syncthreads();
    for (int i = tid; i < cntb; i += 256)
        atomicAdd(&lcur[(opk[i] >> 16) & 255], 1);
    __syncthreads();
    int v = lcur[tid];
    tmp[tid] = v;
    __syncthreads();
    for (int off = 1; off < 256; off <<= 1) {
        int u = (tid >= off) ? tmp[tid - off] : 0;
        __syncthreads();
        tmp[tid] += u;
        __syncthreads();
    }
    int excl = tmp[tid] - v;
    int gbase = gb_sh;
    if (d0 + tid < N) rowptr[d0 + tid] = gbase + excl;
    lcur[tid] = excl;
    __syncthreads();
    for (int i = tid; i < cntb; i += 256) {
        unsigned p = opk[i];
        int pos = atomicAdd(&lcur[(p >> 16) & 255], 1);
        osrc[pos] = (int)(p & 0xFFFFu);
    }
    __syncthreads();
    for (int i = tid; i < cntb; i += 256) ssrc[gbase + i] = osrc[i];
}

// ---------------- attn prep: one wave per node, single gather pass, online softmax ----------------
template <int TAG>
__global__ void attn_prep(const int* __restrict__ rowptr, const int* __restrict__ ssrc,
                          const float* __restrict__ al_s, const float* __restrict__ al_d,
                          float* __restrict__ alog, float* __restrict__ mArr,
                          float* __restrict__ invArr, float* __restrict__ evsArr, int N) {
    int w = (blockIdx.x * blockDim.x + threadIdx.x) >> 6;
    int lane = threadIdx.x & 63;
    if (w >= N) return;
    int beg = rowptr[w], end = rowptr[w + 1];
    float ald = al_d[w];
    float m_l = -1e30f, ss_l = 0.f;
    for (int e = beg + lane; e < end; e += 64) {
        float a = al_s[ssrc[e]] + ald;
        a = (a > 0.f) ? a : 0.2f * a;
        alog[e] = a;
        float Mn = fmaxf(m_l, a);
        ss_l = ss_l * __expf(m_l - Mn) + __expf(a - Mn);
        m_l = Mn;
    }
    for (int off = 32; off; off >>= 1) {
        float m_o = __shfl_xor(m_l, off);
        float s_o = __shfl_xor(ss_l, off);
        float Mn = fmaxf(m_l, m_o);
        ss_l = ss_l * __expf(m_l - Mn) + s_o * __expf(m_o - Mn);
        m_l = Mn;
    }
    float a_self = al_s[w] + ald;
    a_self = (a_self > 0.f) ? a_self : 0.2f * a_self;
    float M2 = fmaxf(m_l, a_self);
    float ss = ss_l * __expf(m_l - M2) + __expf(a_self - M2);
    if (lane == 0) {
        mArr[w] = M2;
        invArr[w] = 1.f / (ss + 1e-16f);
        evsArr[w] = __expf(a_self - M2);
    }
}

// ---------------- gat gather: feature-split (4 chunks x 32 feats), fused BN stats ----------------
template <int TAG>
__global__ void gat_gather(const int* __restrict__ rowptr, const int* __restrict__ ssrc,
                           const float* __restrict__ alog, const float* __restrict__ mArr,
                           const float* __restrict__ invArr, const float* __restrict__ evsArr,
                           const unsigned short* __restrict__ hb, float* __restrict__ out,
                           float* __restrict__ accum8, int N) {
    __shared__ int s_sv[4][64];
    __shared__ float s_at[4][64];
    __shared__ float ys[4][32];
    __shared__ float yq[4][32];
    int tid = threadIdx.x;
    int wiw = tid >> 6;
    int lane = tid & 63;
    int c = blockIdx.x & 3;                 // feature chunk (32 feats = one 64B line/row)
    int w = (blockIdx.x >> 2) * 4 + wiw;    // node
    int sub = lane >> 4;                    // 4 edges in parallel
    int fl = lane & 15;                     // feature pair within chunk
    float acc0 = 0.f, acc1 = 0.f;
    float y0 = 0.f, y1 = 0.f;
    if (w < N) {
        int beg = rowptr[w], end = rowptr[w + 1];
        float Mw = mArr[w];
        for (int base = beg; base < end; base += 64) {
            int nch = min(64, end - base);
            if (lane < nch) {
                s_sv[wiw][lane] = ssrc[base + lane];
                s_at[wiw][lane] = __expf(alog[base + lane] - Mw);
            }
            for (int j0 = 0; j0 < nch; j0 += 16) {
                ushort2 hv[4];
                float av[4];
#pragma unroll
                for (int jj = 0; jj < 4; ++jj) {
                    int j = j0 + 4 * jj + sub;
                    bool ok = j < nch;
                    int sv = ok ? s_sv[wiw][j] : 0;
                    av[jj] = ok ? s_at[wiw][j] : 0.f;
                    hv[jj] = ((const ushort2*)(hb + (size_t)sv * H))[c * 16 + fl];
                }
#pragma unroll
                for (int jj = 0; jj < 4; ++jj) {
                    acc0 += av[jj] * bf2f(hv[jj].x);
                    acc1 += av[jj] * bf2f(hv[jj].y);
                }
            }
        }
        acc0 += __shfl_xor(acc0, 16);
        acc0 += __shfl_xor(acc0, 32);
        acc1 += __shfl_xor(acc1, 16);
        acc1 += __shfl_xor(acc1, 32);
        if (sub == 0) {
            float evs = evsArr[w], inv = invArr[w];
            ushort2 hs = ((const ushort2*)(hb + (size_t)w * H))[c * 16 + fl];
            y0 = (acc0 + evs * bf2f(hs.x)) * inv;
            y1 = (acc1 + evs * bf2f(hs.y)) * inv;
            ((float2*)(out + (size_t)w * H))[c * 16 + fl] = make_float2(y0, y1);
        }
    }
    if (sub == 0) {
        ys[wiw][fl * 2] = y0;
        ys[wiw][fl * 2 + 1] = y1;
        yq[wiw][fl * 2] = y0 * y0;
        yq[wiw][fl * 2 + 1] = y1 * y1;
    }
    __syncthreads();
    if (tid < 32) {
        float s = ys[0][tid] + ys[1][tid] + ys[2][tid] + ys[3][tid];
        float q = yq[0][tid] + yq[1][tid] + yq[2][tid] + yq[3][tid];
        float* ac = accum8 + (size_t)(blockIdx.x & 7) * 256;
        atomicAdd(ac + c * 32 + tid, s);
        atomicAdd(ac + 128 + c * 32 + tid, q);
    }
}

// ---------------- final fc2 ----------------
__global__ void fc2_kernel(const unsigned short* __restrict__ in, const float* __restrict__ w,
                           const float* __restrict__ b, float* __restrict__ out,
                           int N, int OUT) {
    __shared__ float wsm[16 * 132];
    __shared__ float xs[16][129];
    int tid = threadIdx.x;
    for (int i = tid; i < OUT * H; i += 256) {
        int o = i >> 7, k = i & 127;
        wsm[o * 132 + k] = w[i];
    }
    int nb = blockIdx.x * 16;
    for (int i = tid; i < 16 * 128; i += 256) {
        int n = i >> 7, k = i & 127;
        int gn = nb + n;
        xs[n][k] = (gn < N) ? bf2f(in[(size_t)gn * H + k]) : 0.f;
    }
    __syncthreads();
    int o = tid & 15;
    int nn = tid >> 4;
    int n = nb + nn;
    if (n >= N || o >= OUT) return;
    const float* xr = xs[nn];
    const float* wr = wsm + o * 132;
    float acc = b[o];
#pragma unroll 8
    for (int k = 0; k < H; k += 4) {
        acc += xr[k] * wr[k] + xr[k + 1] * wr[k + 1] + xr[k + 2] * wr[k + 2] + xr[k + 3] * wr[k + 3];
    }
    out[(size_t)n * OUT + o] = acc;
}

// ---------------- launch ----------------

extern "C" void kernel_launch(void* const* d_in, const int* in_sizes, int n_in,
                              void* d_out, int out_size, void* d_ws, size_t ws_size,
                              hipStream_t stream) {
    const float* x       = (const float*)d_in[0];
    const int*   ei      = (const int*)d_in[1];
    const float* sat_w   = (const float*)d_in[2];
    const float* sat_b   = (const float*)d_in[3];
    const float* neigh_w = (const float*)d_in[4];
    const float* neigh_b = (const float*)d_in[5];
    const float* fus_w   = (const float*)d_in[6];
    const float* fus_b   = (const float*)d_in[7];
    const float* w1      = (const float*)d_in[8];
    const float* as1     = (const float*)d_in[9];
    const float* ad1     = (const float*)d_in[10];
    const float* g1      = (const float*)d_in[12];
    const float* be1     = (const float*)d_in[13];
    const float* w2      = (const float*)d_in[14];
    const float* as2     = (const float*)d_in[15];
    const float* ad2     = (const float*)d_in[16];
    const float* g2      = (const float*)d_in[18];
    const float* be2     = (const float*)d_in[19];
    const float* fc1_w   = (const float*)d_in[20];
    const float* fc1_b   = (const float*)d_in[21];
    const float* fc2_w   = (const float*)d_in[22];
    const float* fc2_b   = (const float*)d_in[23];

    int N = in_sizes[0] / 64;
    int E = in_sizes[1] / 2;
    int OUT = in_sizes[23];
    int PB = (E + 255) / 256;
    int NBUKET = (N + 255) >> 8;

    float* ws    = (float*)d_ws;
    float* h0    = ws;                      // N*H fp32 (layer2 gat out)
    float* hA    = h0 + (size_t)N * H;      // N*H region: bf16 gemm out + bf16 fuse out
    float* agg   = hA + (size_t)N * H;      // N*H fp32 (layer1 gat out, raw)
    float* al_s  = agg + (size_t)N * H;     // N
    float* al_d  = al_s + N;                // N
    float* mArr  = al_d + N;                // N
    float* invAr = mArr + N;                // N
    float* evsAr = invAr + N;               // N
    float* accum = evsAr + N;               // 4096
    int* rowptr  = (int*)(accum + 4096);    // N+1
    int* cntBB   = rowptr + (N + 1);        // 256*NBSTR
    int* offBB   = cntBB + 256 * NBSTR;     // 256*NBSTR
    int* bukTot  = offBB + 256 * NBSTR;     // 256
    int* ssrc    = bukTot + 256;            // E
    unsigned* pk2= (unsigned*)(ssrc + E);   // E
    float* alog  = (float*)(pk2 + E);       // E
    unsigned* y1b= (unsigned*)(alog + E);   // N*64
    unsigned short* hAb = (unsigned short*)hA;
    unsigned short* h0b = (unsigned short*)(hA + (size_t)N * 64);

    const int* srcp = ei;
    const int* dstp = ei + E;

    dim3 b256(256);
    int gGemm = (N + 63) / 64;
    int gWaveN = (N + 3) / 4;

    // ---- fuse (bf16 out; zeroes accum + bukTot) ----
    fuse_kernel<<<gGemm, b256, 0, stream>>>(x, sat_w, sat_b, neigh_w, neigh_b, fus_w, fus_b,
                                            h0b, accum, bukTot, N);

    // ---- CSR build ----
    pack_bucket<<<256, b256, 0, stream>>>(srcp, dstp, pk2, cntBB, offBB, bukTot, E, PB);
    scatter_sort2<<<NBUKET, b256, 0, stream>>>(pk2, cntBB, offBB, bukTot, ssrc, rowptr, N, E, PB);

    // ================= GAT layer 1 =================
    gemm128m<1, 1><<<gGemm, b256, 0, stream>>>(h0b, w1, nullptr, 0, hAb, N, as1, ad1, al_s, al_d,
                                               nullptr, nullptr, nullptr, nullptr, nullptr);
    attn_prep<1><<<gWaveN, b256, 0, stream>>>(rowptr, ssrc, al_s, al_d, alog, mArr, invAr, evsAr, N);
    gat_gather<1><<<gWaveN * 4, b256, 0, stream>>>(rowptr, ssrc, alog, mArr, invAr, evsAr,
                                                   hAb, agg, accum, N);

    // ================= GAT layer 2 =================
    gemm128m<2, 2><<<gGemm, b256, 0, stream>>>(agg, w2, nullptr, 0, hAb, N, as2, ad2, al_s, al_d,
                                               accum, g1, be1, h0b, y1b);
    attn_prep<2><<<gWaveN, b256, 0, stream>>>(rowptr, ssrc, al_s, al_d, alog, mArr, invAr, evsAr, N);
    gat_gather<2><<<gWaveN * 4, b256, 0, stream>>>(rowptr, ssrc, alog, mArr, invAr, evsAr,
                                                   hAb, h0, accum + 2048, N);

    // ================= head =================
    gemm128m<3, 2><<<gGemm, b256, 0, stream>>>(h0, fc1_w, fc1_b, 1, hAb, N, nullptr, nullptr,
                                               nullptr, nullptr, accum + 2048, g2, be2,
                                               (const unsigned short*)y1b, nullptr);
    fc2_kernel<<<(N + 15) / 16, b256, 0, stream>>>(hAb, fc2_w, fc2_b, (float*)d_out, N, OUT);
}

// Round 23
// 299.082 us; speedup vs baseline: 1.5250x; 1.5250x over previous
//
#include <hip/hip_runtime.h>

#define H 128

typedef __attribute__((ext_vector_type(8))) short bf16x8;
typedef __attribute__((ext_vector_type(4))) float f32x4;

__device__ __forceinline__ float bf2f(unsigned short u) {
    return __uint_as_float(((unsigned)u) << 16);
}
__device__ __forceinline__ unsigned short f2bf(float f) {
    unsigned u = __float_as_uint(f);
    unsigned r = (u + 0x7fffu + ((u >> 16) & 1u)) >> 16;
    return (unsigned short)r;
}
__device__ __forceinline__ unsigned pack2bf(float a, float b) {
    return (unsigned)f2bf(a) | ((unsigned)f2bf(b) << 16);
}

// ---------------- fuse: MFMA K=32, bf16 out (+ zeroes accum/bukTot in block 0) ----------------
__global__ void fuse_kernel(const float* __restrict__ x,
                            const float* __restrict__ sat_w, const float* __restrict__ sat_b,
                            const float* __restrict__ neigh_w, const float* __restrict__ neigh_b,
                            const float* __restrict__ fus_w, const float* __restrict__ fus_b,
                            unsigned short* __restrict__ h0b,
                            float* __restrict__ accum, int* __restrict__ bukTot, int N) {
    __shared__ unsigned smem[8512];
    __shared__ float reds[4][64];
    unsigned* a_lds = smem;          // [node][kp] kp<32, stride 36
    unsigned* w_lds = smem + 2304;   // [feat 0..255][kp] kp<16, stride 20
    int tid = threadIdx.x;
    int base = blockIdx.x * 64;
    if (blockIdx.x == 0) {
        for (int i = tid; i < 4096; i += 256) accum[i] = 0.f;
        bukTot[tid] = 0;
    }
    for (int i = tid; i < 64 * 32; i += 256) {
        int n = i >> 5, kp = i & 31;
        int gn = base + n;
        float2 v = (gn < N) ? *(const float2*)(x + (size_t)gn * 64 + kp * 2) : make_float2(0.f, 0.f);
        a_lds[n * 36 + kp] = pack2bf(v.x, v.y);
    }
    for (int i = tid; i < 256 * 16; i += 256) {
        int r = i >> 4, kp = i & 15;
        const float* wsrc = (r < 128) ? (sat_w + (size_t)r * 32) : (neigh_w + (size_t)(r - 128) * 32);
        float2 v = *(const float2*)(wsrc + kp * 2);
        w_lds[r * 20 + kp] = pack2bf(v.x, v.y);
    }
    __syncthreads();
    int lane = tid & 63;
    int wv = tid >> 6;
    int lr = lane & 15, lk = lane >> 4;
    f32x4 accS[4][2], accN[4][2];
#pragma unroll
    for (int r = 0; r < 4; ++r)
#pragma unroll
        for (int t = 0; t < 2; ++t) {
            accS[r][t] = (f32x4){0.f, 0.f, 0.f, 0.f};
            accN[r][t] = (f32x4){0.f, 0.f, 0.f, 0.f};
        }
    bf16x8 afS[4], afN[4];
#pragma unroll
    for (int r = 0; r < 4; ++r) {
        afS[r] = *(const bf16x8*)&a_lds[(r * 16 + lr) * 36 + lk * 4];
        afN[r] = *(const bf16x8*)&a_lds[(r * 16 + lr) * 36 + 16 + lk * 4];
    }
#pragma unroll
    for (int t = 0; t < 2; ++t) {
        bf16x8 bS = *(const bf16x8*)&w_lds[(wv * 32 + t * 16 + lr) * 20 + lk * 4];
        bf16x8 bN = *(const bf16x8*)&w_lds[(128 + wv * 32 + t * 16 + lr) * 20 + lk * 4];
#pragma unroll
        for (int r = 0; r < 4; ++r) {
            accS[r][t] = __builtin_amdgcn_mfma_f32_16x16x32_bf16(afS[r], bS, accS[r][t], 0, 0, 0);
            accN[r][t] = __builtin_amdgcn_mfma_f32_16x16x32_bf16(afN[r], bN, accN[r][t], 0, 0, 0);
        }
    }
    __syncthreads();
    unsigned short* cst = (unsigned short*)smem; // [64][266]
#pragma unroll
    for (int t = 0; t < 2; ++t) {
        int col = wv * 32 + t * 16 + lr;
        float sb = sat_b[col], nb = neigh_b[col];
#pragma unroll
        for (int r = 0; r < 4; ++r) {
#pragma unroll
            for (int j = 0; j < 4; ++j) {
                int srow = r * 16 + lk * 4 + j;
                cst[srow * 266 + col] = f2bf(fmaxf(accS[r][t][j] + sb, 0.f));
                cst[srow * 266 + 133 + col] = f2bf(fmaxf(accN[r][t][j] + nb, 0.f));
            }
        }
    }
    __syncthreads();
    int node = tid & 63;
    int part = tid >> 6;
    float ps = 0.f;
#pragma unroll
    for (int k = 0; k < 32; ++k) {
        int col = part * 32 + k;
        ps += bf2f(cst[node * 266 + col]) * fus_w[col]
            + bf2f(cst[node * 266 + 133 + col]) * fus_w[128 + col];
    }
    reds[part][node] = ps;
    __syncthreads();
    float tot = reds[0][node] + reds[1][node] + reds[2][node] + reds[3][node];
    float g = 1.f / (1.f + __expf(-(tot + fus_b[0])));
    if (base + node < N) {
        unsigned* op = (unsigned*)h0b + (size_t)(base + node) * 64 + part * 16;
#pragma unroll
        for (int kp = 0; kp < 16; ++kp) {
            int col = part * 32 + kp * 2;
            float o0 = g * bf2f(cst[node * 266 + col]) + (1.f - g) * bf2f(cst[node * 266 + 133 + col]);
            float o1 = g * bf2f(cst[node * 266 + col + 1]) + (1.f - g) * bf2f(cst[node * 266 + 134 + col]);
            op[kp] = pack2bf(o0, o1);
        }
    }
}

// ---------------- MFMA bf16 GEMM: 64 nodes x 128 cols per block ----------------
// MODE 1 = bf16 input; MODE 2 = fused-BN input (fp32 raw + in-block scale/shift from accum8
//          + bf16 residual, optional bf16 y-out)
template <int TAG, int MODE>
__global__ void gemm128m(const void* __restrict__ inv, const float* __restrict__ w,
                         const float* __restrict__ bias, int do_relu,
                         unsigned short* __restrict__ outb, int N,
                         const float* __restrict__ a_sp, const float* __restrict__ a_dp,
                         float* __restrict__ al_s, float* __restrict__ al_d,
                         const float* __restrict__ accum8, const float* __restrict__ gvec,
                         const float* __restrict__ bevec,
                         const unsigned short* __restrict__ resb, unsigned* __restrict__ yout) {
    __shared__ unsigned a_lds[64 * 68];
    __shared__ unsigned w_lds[128 * 68];
    __shared__ float reds[4][64];
    __shared__ float redd[4][64];
    __shared__ float sc_l[128], sh_l[128];
    int tid = threadIdx.x;
    int base = blockIdx.x * 64;
    if (MODE == 2) {
        if (tid < 128) {
            float s = 0.f, q = 0.f;
#pragma unroll
            for (int c = 0; c < 8; ++c) {
                s += accum8[c * 256 + tid];
                q += accum8[c * 256 + 128 + tid];
            }
            float Ninv = 1.f / (float)N;
            float mu = s * Ninv;
            float var = q * Ninv - mu * mu;
            float sc = rsqrtf(var + 1e-5f) * gvec[tid];
            sc_l[tid] = sc;
            sh_l[tid] = bevec[tid] - mu * sc;
        }
        __syncthreads();
    }
    for (int i = tid; i < 64 * 64; i += 256) {
        int n = i >> 6, kp = i & 63;
        int gn = base + n;
        unsigned p = 0u;
        if (gn < N) {
            if (MODE == 1) {
                p = ((const unsigned*)inv)[(size_t)gn * 64 + kp];
            } else {
                float2 v = *(const float2*)((const float*)inv + (size_t)gn * 128 + kp * 2);
                float2 sc = ((const float2*)sc_l)[kp];
                float2 sh = ((const float2*)sh_l)[kp];
                ushort2 rr = ((const ushort2*)(resb + (size_t)gn * 128))[kp];
                float y0 = fmaxf(v.x * sc.x + sh.x, 0.f) + bf2f(rr.x);
                float y1 = fmaxf(v.y * sc.y + sh.y, 0.f) + bf2f(rr.y);
                p = pack2bf(y0, y1);
                if (yout) yout[(size_t)gn * 64 + kp] = p;
            }
        }
        a_lds[n * 68 + kp] = p;
    }
    for (int i = tid; i < 128 * 64; i += 256) {
        int c = i >> 6, kp = i & 63;
        float2 v = *(const float2*)(w + (size_t)c * 128 + kp * 2);
        w_lds[c * 68 + kp] = pack2bf(v.x, v.y);
    }
    __syncthreads();
    int lane = tid & 63;
    int wv = tid >> 6;
    int lr = lane & 15;
    int lk = lane >> 4;
    f32x4 acc[4][2];
#pragma unroll
    for (int r = 0; r < 4; ++r)
#pragma unroll
        for (int t = 0; t < 2; ++t) acc[r][t] = (f32x4){0.f, 0.f, 0.f, 0.f};
    for (int c = 0; c < 4; ++c) {
        bf16x8 af[4], bfr[2];
#pragma unroll
        for (int r = 0; r < 4; ++r)
            af[r] = *(const bf16x8*)&a_lds[(r * 16 + lr) * 68 + c * 16 + lk * 4];
#pragma unroll
        for (int t = 0; t < 2; ++t)
            bfr[t] = *(const bf16x8*)&w_lds[(wv * 32 + t * 16 + lr) * 68 + c * 16 + lk * 4];
#pragma unroll
        for (int r = 0; r < 4; ++r)
#pragma unroll
            for (int t = 0; t < 2; ++t)
                acc[r][t] = __builtin_amdgcn_mfma_f32_16x16x32_bf16(af[r], bfr[t], acc[r][t], 0, 0, 0);
    }
    __syncthreads();
    unsigned short* cst = (unsigned short*)a_lds; // [64][136]
#pragma unroll
    for (int t = 0; t < 2; ++t) {
        int col = wv * 32 + t * 16 + lr;
        float bv = bias ? bias[col] : 0.f;
#pragma unroll
        for (int r = 0; r < 4; ++r) {
#pragma unroll
            for (int j = 0; j < 4; ++j) {
                float v = acc[r][t][j] + bv;
                if (do_relu) v = fmaxf(v, 0.f);
                cst[(r * 16 + lk * 4 + j) * 136 + col] = f2bf(v);
            }
        }
    }
    __syncthreads();
    for (int i = tid; i < 64 * 64; i += 256) {
        int n = i >> 6, kp = i & 63;
        int gn = base + n;
        if (gn < N) ((unsigned*)outb)[(size_t)gn * 64 + kp] = a_lds[n * 68 + kp];
    }
    if (a_sp) {
        int node = tid & 63;
        int part = tid >> 6;
        float ps = 0.f, pd = 0.f;
        int kb = part * 32;
        const unsigned short* xr = cst + node * 136 + kb;
#pragma unroll
        for (int k = 0; k < 32; ++k) {
            float v = bf2f(xr[k]);
            ps += v * a_sp[kb + k];
            pd += v * a_dp[kb + k];
        }
        reds[part][node] = ps;
        redd[part][node] = pd;
        __syncthreads();
        if (tid < 64) {
            int gn = base + tid;
            if (gn < N) {
                al_s[gn] = reds[0][tid] + reds[1][tid] + reds[2][tid] + reds[3][tid];
                al_d[gn] = redd[0][tid] + redd[1][tid] + redd[2][tid] + redd[3][tid];
            }
        }
    }
}

// ---------------- CSR build: streaming bucket sort (256 pack blocks, N <= 65536) ----------------
#define PBMAX 6400
#define NBSTR 256
__global__ void pack_bucket(const int* __restrict__ src, const int* __restrict__ dst,
                            unsigned* __restrict__ pk2, int* __restrict__ cntBB,
                            int* __restrict__ offBB, int* __restrict__ bukTot, int E, int PB) {
    __shared__ unsigned opk[PBMAX];
    __shared__ unsigned opk2[PBMAX];
    __shared__ int lcnt[256];
    __shared__ int tmp[256];
    int tid = threadIdx.x;
    int blk = blockIdx.x;
    int e0 = blk * PB;
    int n = min(PB, E - e0);
    if (n < 0) n = 0;
    lcnt[tid] = 0;
    __syncthreads();
    for (int i = tid; i < n; i += 256) {
        int s = src[e0 + i];
        int d = dst[e0 + i];
        unsigned p = ((unsigned)d << 16) | (unsigned)s;
        opk[i] = p;
        atomicAdd(&lcnt[d >> 8], 1);
    }
    __syncthreads();
    int v = lcnt[tid];
    tmp[tid] = v;
    __syncthreads();
    for (int off = 1; off < 256; off <<= 1) {
        int u = (tid >= off) ? tmp[tid - off] : 0;
        __syncthreads();
        tmp[tid] += u;
        __syncthreads();
    }
    int excl = tmp[tid] - v;
    cntBB[(size_t)tid * NBSTR + blk] = v;    // [bucket][block]
    offBB[(size_t)tid * NBSTR + blk] = excl; // [bucket][block]
    if (v > 0) atomicAdd(&bukTot[tid], v);
    lcnt[tid] = excl; // cursor
    __syncthreads();
    for (int i = tid; i < n; i += 256) {
        unsigned p = opk[i];
        int pos = atomicAdd(&lcnt[(p >> 16) >> 8], 1);
        opk2[pos] = p;
    }
    __syncthreads();
    for (int i = tid; i < n; i += 256) pk2[e0 + i] = opk2[i];
}

// per-bucket: LDS-staged edges, direct-indexed counting sort, coalesced ssrc + direct rowptr.
#define BCAP 10240
__global__ void scatter_sort2(const unsigned* __restrict__ pk2, const int* __restrict__ cntBB,
                              const int* __restrict__ offBB, const int* __restrict__ bukTot,
                              int* __restrict__ ssrc, int* __restrict__ rowptr,
                              int N, int E, int PB) {
    __shared__ int segoff[257];
    __shared__ int segsrc[256];
    __shared__ int segcnt[256];
    __shared__ int lcur[256];
    __shared__ int tmp[256];
    __shared__ int bt[256];
    __shared__ int gb_sh;
    __shared__ unsigned opk[BCAP];
    __shared__ int osrc[BCAP];
    int b = blockIdx.x;
    int d0 = b << 8;
    int tid = threadIdx.x;
    int btv = bukTot[tid];
    bt[tid] = btv;
    tmp[tid] = btv;
    __syncthreads();
    for (int off = 1; off < 256; off <<= 1) {
        int u = (tid >= off) ? tmp[tid - off] : 0;
        __syncthreads();
        tmp[tid] += u;
        __syncthreads();
    }
    if (tid == 0) {
        gb_sh = tmp[b] - bt[b];
        if (b == 0) rowptr[N] = E;
    }
    __syncthreads();
    int c = cntBB[(size_t)b * NBSTR + tid];   // coalesced
    segcnt[tid] = c;
    segsrc[tid] = tid * PB + offBB[(size_t)b * NBSTR + tid];
    tmp[tid] = c;
    lcur[tid] = 0;
    __syncthreads();
    for (int off = 1; off < 256; off <<= 1) {
        int u = (tid >= off) ? tmp[tid - off] : 0;
        __syncthreads();
        tmp[tid] += u;
        __syncthreads();
    }
    segoff[tid] = tmp[tid] - segcnt[tid];
    if (tid == 255) segoff[256] = tmp[255];
    __syncthreads();
    int cntb = segoff[256];
    int wv = tid >> 6, lane = tid & 63;
    for (int s = wv; s < 256; s += 4) {
        int sc = segcnt[s], so = segoff[s], gs = segsrc[s];
        for (int i = lane; i < sc; i += 64) opk[so + i] = pk2[gs + i];
    }
    __syncthreads();
    for (int i = tid; i < cntb; i += 256)
        atomicAdd(&lcur[(opk[i] >> 16) & 255], 1);
    __syncthreads();
    int v = lcur[tid];
    tmp[tid] = v;
    __syncthreads();
    for (int off = 1; off < 256; off <<= 1) {
        int u = (tid >= off) ? tmp[tid - off] : 0;
        __syncthreads();
        tmp[tid] += u;
        __syncthreads();
    }
    int excl = tmp[tid] - v;
    int gbase = gb_sh;
    if (d0 + tid < N) rowptr[d0 + tid] = gbase + excl;
    lcur[tid] = excl; // cursor
    __syncthreads();
    for (int i = tid; i < cntb; i += 256) {
        unsigned p = opk[i];
        int pos = atomicAdd(&lcur[(p >> 16) & 255], 1);
        osrc[pos] = (int)(p & 0xFFFFu);
    }
    __syncthreads();
    for (int i = tid; i < cntb; i += 256) ssrc[gbase + i] = osrc[i];
}

// ---------------- GAT aggregation (edge-pair halves) + fused BN stats ----------------
template <int TAG>
__global__ void gat_agg(const int* __restrict__ rowptr, const int* __restrict__ ssrc,
                        const float* __restrict__ al_s, const float* __restrict__ al_d,
                        const unsigned short* __restrict__ hb, float* __restrict__ out,
                        float* __restrict__ accum8, int N) {
    __shared__ int s_sv[4][64];
    __shared__ float s_ev[4][64];
    __shared__ float ys[4][128];
    __shared__ float yq[4][128];
    int tid = threadIdx.x;
    int wiw = tid >> 6;
    int w = (blockIdx.x * blockDim.x + tid) >> 6;
    int lane = tid & 63;
    int sub = lane >> 5;
    int fl = lane & 31;
    float a0 = 0.f, a1 = 0.f, a2 = 0.f, a3 = 0.f;
    float ss = 0.f;
    if (w < N) {
        int beg = rowptr[w], end = rowptr[w + 1];
        float ald = al_d[w];
        float a_self = al_s[w] + ald;
        a_self = (a_self > 0.f) ? a_self : 0.2f * a_self;
        float m = a_self;
        for (int e = beg + lane; e < end; e += 64) {
            float a = al_s[ssrc[e]] + ald;
            a = (a > 0.f) ? a : 0.2f * a;
            m = fmaxf(m, a);
        }
        for (int off = 32; off; off >>= 1) m = fmaxf(m, __shfl_xor(m, off));
        for (int base = beg; base < end; base += 64) {
            int nch = min(64, end - base);
            int sv = 0;
            float ev = 0.f;
            if (lane < nch) {
                sv = ssrc[base + lane];
                float a = al_s[sv] + ald;
                a = (a > 0.f) ? a : 0.2f * a;
                ev = __expf(a - m);
            }
            ss += ev;
            s_sv[wiw][lane] = sv;
            s_ev[wiw][lane] = ev;
            for (int j0 = 0; j0 < nch; j0 += 8) {
                ushort4 hv[4];
                float evv[4];
#pragma unroll
                for (int jj = 0; jj < 4; ++jj) {
                    int j = j0 + 2 * jj + sub;
                    bool ok = j < nch;
                    int svj = ok ? s_sv[wiw][j] : 0;
                    evv[jj] = ok ? s_ev[wiw][j] : 0.f;
                    hv[jj] = ((const ushort4*)(hb + (size_t)svj * H))[fl];
                }
#pragma unroll
                for (int jj = 0; jj < 4; ++jj) {
                    a0 += evv[jj] * bf2f(hv[jj].x);
                    a1 += evv[jj] * bf2f(hv[jj].y);
                    a2 += evv[jj] * bf2f(hv[jj].z);
                    a3 += evv[jj] * bf2f(hv[jj].w);
                }
            }
        }
        for (int off = 32; off; off >>= 1) ss += __shfl_xor(ss, off);
        a0 += __shfl_xor(a0, 32);
        a1 += __shfl_xor(a1, 32);
        a2 += __shfl_xor(a2, 32);
        a3 += __shfl_xor(a3, 32);
        float ev_self = __expf(a_self - m);
        ss += ev_self;
        ushort4 hs = ((const ushort4*)(hb + (size_t)w * H))[fl];
        a0 += ev_self * bf2f(hs.x);
        a1 += ev_self * bf2f(hs.y);
        a2 += ev_self * bf2f(hs.z);
        a3 += ev_self * bf2f(hs.w);
        float inv = 1.f / (ss + 1e-16f);
        a0 *= inv; a1 *= inv; a2 *= inv; a3 *= inv;
        if (sub == 0) {
            ((float4*)(out + (size_t)w * H))[fl] = make_float4(a0, a1, a2, a3);
        }
    }
    if (sub == 0) {
        float4 yy = (w < N) ? make_float4(a0, a1, a2, a3) : make_float4(0.f, 0.f, 0.f, 0.f);
        ((float4*)&ys[wiw][0])[fl] = yy;
        ((float4*)&yq[wiw][0])[fl] = make_float4(yy.x * yy.x, yy.y * yy.y, yy.z * yy.z, yy.w * yy.w);
    }
    __syncthreads();
    if (tid < 128) {
        float s = ys[0][tid] + ys[1][tid] + ys[2][tid] + ys[3][tid];
        float q = yq[0][tid] + yq[1][tid] + yq[2][tid] + yq[3][tid];
        float* ac = accum8 + (size_t)(blockIdx.x & 7) * 256;
        atomicAdd(ac + tid, s);
        atomicAdd(ac + 128 + tid, q);
    }
}

// ---------------- final fc2: bf16 input rows staged in LDS ----------------
__global__ void fc2_kernel(const unsigned short* __restrict__ in, const float* __restrict__ w,
                           const float* __restrict__ b, float* __restrict__ out,
                           int N, int OUT) {
    __shared__ float wsm[16 * 132];
    __shared__ float xs[16][129];
    int tid = threadIdx.x;
    for (int i = tid; i < OUT * H; i += 256) {
        int o = i >> 7, k = i & 127;
        wsm[o * 132 + k] = w[i];
    }
    int nb = blockIdx.x * 16;
    for (int i = tid; i < 16 * 128; i += 256) {
        int n = i >> 7, k = i & 127;
        int gn = nb + n;
        xs[n][k] = (gn < N) ? bf2f(in[(size_t)gn * H + k]) : 0.f;
    }
    __syncthreads();
    int o = tid & 15;
    int nn = tid >> 4;
    int n = nb + nn;
    if (n >= N || o >= OUT) return;
    const float* xr = xs[nn];
    const float* wr = wsm + o * 132;
    float acc = b[o];
#pragma unroll 8
    for (int k = 0; k < H; k += 4) {
        acc += xr[k] * wr[k] + xr[k + 1] * wr[k + 1] + xr[k + 2] * wr[k + 2] + xr[k + 3] * wr[k + 3];
    }
    out[(size_t)n * OUT + o] = acc;
}

// ---------------- launch ----------------

extern "C" void kernel_launch(void* const* d_in, const int* in_sizes, int n_in,
                              void* d_out, int out_size, void* d_ws, size_t ws_size,
                              hipStream_t stream) {
    const float* x       = (const float*)d_in[0];
    const int*   ei      = (const int*)d_in[1];
    const float* sat_w   = (const float*)d_in[2];
    const float* sat_b   = (const float*)d_in[3];
    const float* neigh_w = (const float*)d_in[4];
    const float* neigh_b = (const float*)d_in[5];
    const float* fus_w   = (const float*)d_in[6];
    const float* fus_b   = (const float*)d_in[7];
    const float* w1      = (const float*)d_in[8];
    const float* as1     = (const float*)d_in[9];
    const float* ad1     = (const float*)d_in[10];
    const float* g1      = (const float*)d_in[12];
    const float* be1     = (const float*)d_in[13];
    const float* w2      = (const float*)d_in[14];
    const float* as2     = (const float*)d_in[15];
    const float* ad2     = (const float*)d_in[16];
    const float* g2      = (const float*)d_in[18];
    const float* be2     = (const float*)d_in[19];
    const float* fc1_w   = (const float*)d_in[20];
    const float* fc1_b   = (const float*)d_in[21];
    const float* fc2_w   = (const float*)d_in[22];
    const float* fc2_b   = (const float*)d_in[23];

    int N = in_sizes[0] / 64;
    int E = in_sizes[1] / 2;
    int OUT = in_sizes[23];
    int PB = (E + 255) / 256;
    int NBUKET = (N + 255) >> 8;

    float* ws    = (float*)d_ws;
    float* h0    = ws;                      // N*H fp32 (layer2 gat out)
    float* hA    = h0 + (size_t)N * H;      // N*H region: bf16 gemm out + bf16 fuse out
    float* agg   = hA + (size_t)N * H;      // N*H fp32 (layer1 gat out, raw)
    float* al_s  = agg + (size_t)N * H;     // N
    float* al_d  = al_s + N;                // N
    float* accum = al_d + N;                // 4096
    int* rowptr  = (int*)(accum + 4096);    // N+1
    int* cntBB   = rowptr + (N + 1);        // 256*NBSTR ([bucket][block])
    int* offBB   = cntBB + 256 * NBSTR;     // 256*NBSTR
    int* bukTot  = offBB + 256 * NBSTR;     // 256
    int* ssrc    = bukTot + 256;            // E
    unsigned* pk2= (unsigned*)(ssrc + E);   // E
    unsigned* y1b= pk2 + E;                 // N*64 (bf16 layer1 output, residual for layer2)
    unsigned short* hAb = (unsigned short*)hA;
    unsigned short* h0b = (unsigned short*)(hA + (size_t)N * 64);

    const int* srcp = ei;
    const int* dstp = ei + E;

    dim3 b256(256);
    int gGemm = (N + 63) / 64;
    int gWaveN = (N + 3) / 4;

    // ---- fuse (bf16 out; zeroes accum + bukTot) ----
    fuse_kernel<<<gGemm, b256, 0, stream>>>(x, sat_w, sat_b, neigh_w, neigh_b, fus_w, fus_b,
                                            h0b, accum, bukTot, N);

    // ---- CSR build (streaming bucket sort; no single-block kernels) ----
    pack_bucket<<<256, b256, 0, stream>>>(srcp, dstp, pk2, cntBB, offBB, bukTot, E, PB);
    scatter_sort2<<<NBUKET, b256, 0, stream>>>(pk2, cntBB, offBB, bukTot, ssrc, rowptr, N, E, PB);

    // ================= GAT layer 1 =================
    gemm128m<1, 1><<<gGemm, b256, 0, stream>>>(h0b, w1, nullptr, 0, hAb, N, as1, ad1, al_s, al_d,
                                               nullptr, nullptr, nullptr, nullptr, nullptr);
    gat_agg<1><<<gWaveN, b256, 0, stream>>>(rowptr, ssrc, al_s, al_d, hAb, agg, accum, N);

    // ================= GAT layer 2 (gemm fuses bn1+relu+residual; emits y1b) =================
    gemm128m<2, 2><<<gGemm, b256, 0, stream>>>(agg, w2, nullptr, 0, hAb, N, as2, ad2, al_s, al_d,
                                               accum, g1, be1, h0b, y1b);
    gat_agg<2><<<gWaveN, b256, 0, stream>>>(rowptr, ssrc, al_s, al_d, hAb, h0, accum + 2048, N);

    // ================= head (gemm fuses bn2+relu+residual) =================
    gemm128m<3, 2><<<gGemm, b256, 0, stream>>>(h0, fc1_w, fc1_b, 1, hAb, N, nullptr, nullptr,
                                               nullptr, nullptr, accum + 2048, g2, be2,
                                               (const unsigned short*)y1b, nullptr);
    fc2_kernel<<<(N + 15) / 16, b256, 0, stream>>>(hAb, fc2_w, fc2_b, (float*)d_out, N, OUT);
}